// Round 10
// baseline (650.043 us; speedup 1.0000x reference)
//
#include <hip/hip_runtime.h>
#include <hip/hip_fp16.h>
#include <math.h>

#define N_NODES 100000
#define DIM 64
#define E_REL 1600000
#define E_QQ 1000000

#define NBUCK 196      // ceil(100000 / 512) node buckets of 512
#define BCAP 9216      // capacity per bucket; expected 8192, +11 sigma slack
#define CHUNK_E 4096   // edges per phase-1 block -> 391 blocks (occupancy)
#define P1_BLOCKS ((E_REL + CHUNK_E - 1) / CHUNK_E)
#define MID_BLOCKS 1536            // 6 blocks/CU (25 KB LDS each)
#define MID_STRIDE (MID_BLOCKS * 32)
#define FIN_BLOCKS 2048            // 8 blocks/CU (1 KB LDS)
#define FIN_STRIDE (FIN_BLOCKS * 32)

// ---------------------------------------------------------------------------
// Phase 1: bin edges by dst-bucket (packed (dlocal<<17)|src) and by src-bucket
// (raw src). Per-block LDS counts; ~2*NBUCK global atomics per block reserve
// space; placement via LDS cursors. int4-vectorized edge reads.
// ---------------------------------------------------------------------------
__global__ __launch_bounds__(256) void bin_edges(
    const int* __restrict__ src, const int* __restrict__ dst,
    int* __restrict__ gcur_d, int* __restrict__ gcur_s,
    unsigned* __restrict__ bin_d, unsigned* __restrict__ bin_s) {
  __shared__ int cd[NBUCK];
  __shared__ int cs[NBUCK];
  int t = threadIdx.x;
  for (int i = t; i < NBUCK; i += 256) { cd[i] = 0; cs[i] = 0; }
  __syncthreads();
  int e0 = blockIdx.x * CHUNK_E;
  int n = E_REL - e0;
  if (n > CHUNK_E) n = CHUNK_E;
  int n4 = n >> 2;  // chunk sizes (4096 / 2560 tail) are multiples of 4
  const int4* s4 = (const int4*)(src + e0);
  const int4* d4 = (const int4*)(dst + e0);
  for (int i = t; i < n4; i += 256) {
    int4 dv = d4[i];
    atomicAdd(&cd[dv.x >> 9], 1);
    atomicAdd(&cd[dv.y >> 9], 1);
    atomicAdd(&cd[dv.z >> 9], 1);
    atomicAdd(&cd[dv.w >> 9], 1);
    int4 sv = s4[i];
    atomicAdd(&cs[sv.x >> 9], 1);
    atomicAdd(&cs[sv.y >> 9], 1);
    atomicAdd(&cs[sv.z >> 9], 1);
    atomicAdd(&cs[sv.w >> 9], 1);
  }
  __syncthreads();
  for (int i = t; i < NBUCK; i += 256) {
    int c = cd[i];
    cd[i] = c > 0 ? atomicAdd(&gcur_d[i], c) : 0;
    c = cs[i];
    cs[i] = c > 0 ? atomicAdd(&gcur_s[i], c) : 0;
  }
  __syncthreads();
  for (int i = t; i < n4; i += 256) {
    int4 sv = s4[i];
    int4 dv = d4[i];
#pragma unroll
    for (int k = 0; k < 4; k++) {
      int s = (&sv.x)[k];
      int d = (&dv.x)[k];
      int bd = d >> 9;
      int bs = s >> 9;
      int pd = atomicAdd(&cd[bd], 1);
      int ps = atomicAdd(&cs[bs], 1);
      if ((unsigned)pd < BCAP)
        bin_d[(size_t)bd * BCAP + pd] = (unsigned)(((d & 511) << 17) | s);
      if ((unsigned)ps < BCAP)
        bin_s[(size_t)bs * BCAP + ps] = (unsigned)s;
    }
  }
}

// ---------------------------------------------------------------------------
// Phase 2 fused: blocks 0..NBUCK-1 build the dst-CSR with SLICE-ORDERED
// per-node src lists (4096-bin (dlocal<<3|src>>14) histogram -> scan ->
// compact). Blocks NBUCK..2*NBUCK-1 build csrc = rsqrt(outdeg).
// ---------------------------------------------------------------------------
__global__ __launch_bounds__(256) void build_tables(
    const unsigned* __restrict__ bin_d, const int* __restrict__ gcur_d,
    const unsigned* __restrict__ bin_s, const int* __restrict__ gcur_s,
    int* __restrict__ offs, int* __restrict__ degv, int* __restrict__ srclist,
    float* __restrict__ csrc) {
  __shared__ int cnt[4096];
  __shared__ int curv[4096];
  __shared__ int ls[256];
  int t = threadIdx.x;
  if (blockIdx.x >= NBUCK) {
    // ---- src histogram -> csrc ----
    int b = blockIdx.x - NBUCK;
    cnt[t] = 0;
    cnt[t + 256] = 0;
    __syncthreads();
    int n = gcur_s[b];
    if (n > BCAP) n = BCAP;
    const unsigned* be = bin_s + (size_t)b * BCAP;
    for (int i = t; i < n; i += 256) atomicAdd(&cnt[be[i] & 511], 1);
    __syncthreads();
    int node0 = b << 9;
    for (int i = t; i < 512; i += 256) {
      int node = node0 + i;
      if (node < N_NODES) {
        int d = cnt[i];
        csrc[node] = d > 0 ? rsqrtf((float)d) : 0.0f;
      }
    }
    return;
  }
  // ---- dst CSR, slice-ordered ----
  int b = blockIdx.x;
  for (int i = t; i < 4096; i += 256) cnt[i] = 0;
  __syncthreads();
  int n = gcur_d[b];
  if (n > BCAP) n = BCAP;
  const unsigned* be = bin_d + (size_t)b * BCAP;
  // bin = (dlocal<<3) | slice, slice = src>>14 in 0..6
  for (int i = t; i < n; i += 256) {
    unsigned p = be[i];
    int bin = (int)((p >> 17) << 3) | (int)((p & 0x1FFFFu) >> 14);
    atomicAdd(&cnt[bin], 1);
  }
  __syncthreads();
  // block scan over 4096 bins: 16 serial per thread + 256-wide scan
  int partial = 0;
#pragma unroll
  for (int i = 0; i < 16; i++) partial += cnt[t * 16 + i];
  ls[t] = partial;
  __syncthreads();
  for (int off = 1; off < 256; off <<= 1) {
    int v = (t >= off) ? ls[t - off] : 0;
    __syncthreads();
    ls[t] += v;
    __syncthreads();
  }
  int run = ls[t] - partial;
#pragma unroll
  for (int i = 0; i < 16; i++) {
    int bin = t * 16 + i;
    curv[bin] = run;
    run += cnt[bin];
  }
  __syncthreads();
  // write per-node outputs BEFORE placement mutates curv
  int node0 = b << 9;
  for (int i = t; i < 512; i += 256) {
    int node = node0 + i;
    if (node < N_NODES) {
      int deg = 0;
#pragma unroll
      for (int s = 0; s < 8; s++) deg += cnt[i * 8 + s];
      offs[node] = b * BCAP + curv[i * 8];
      degv[node] = deg;
    }
  }
  __syncthreads();
  for (int i = t; i < n; i += 256) {
    unsigned p = be[i];
    int bin = (int)((p >> 17) << 3) | (int)((p & 0x1FFFFu) >> 14);
    int pos = atomicAdd(&curv[bin], 1);
    srclist[(size_t)b * BCAP + pos] = (int)(p & 0x1FFFF);
  }
}

__device__ inline unsigned pack_h2(float a, float b) {
  __half2 h = __floats2half2_rn(a, b);
  return *reinterpret_cast<unsigned*>(&h);
}

// ---------------------------------------------------------------------------
// Y[row] = fp16( csrc[row] * (X[row] @ W) )   thread-per-row, W in LDS
// ---------------------------------------------------------------------------
__global__ __launch_bounds__(256) void gemm_in_h(
    const float* __restrict__ X, const float* __restrict__ W,
    const float* __restrict__ csrc, __half* __restrict__ Y) {
  __shared__ float Ws[64 * 64];
  for (int t = threadIdx.x; t < 64 * 64; t += 256) Ws[t] = W[t];
  __syncthreads();
  int row = blockIdx.x * 256 + threadIdx.x;
  if (row >= N_NODES) return;
  const float4* xr = (const float4*)(X + (size_t)row * 64);
  float acc[64];
#pragma unroll
  for (int j = 0; j < 64; j++) acc[j] = 0.0f;
#pragma unroll
  for (int k4 = 0; k4 < 16; k4++) {
    float4 xv = xr[k4];
    const float* w0 = &Ws[(k4 * 4 + 0) * 64];
    const float* w1 = &Ws[(k4 * 4 + 1) * 64];
    const float* w2 = &Ws[(k4 * 4 + 2) * 64];
    const float* w3 = &Ws[(k4 * 4 + 3) * 64];
#pragma unroll
    for (int j = 0; j < 64; j++)
      acc[j] += xv.x * w0[j] + xv.y * w1[j] + xv.z * w2[j] + xv.w * w3[j];
  }
  float s = csrc[row];
  uint4* yr = (uint4*)(Y + (size_t)row * 64);
#pragma unroll
  for (int j8 = 0; j8 < 8; j8++) {
    uint4 u;
    u.x = pack_h2(s * acc[j8 * 8 + 0], s * acc[j8 * 8 + 1]);
    u.y = pack_h2(s * acc[j8 * 8 + 2], s * acc[j8 * 8 + 3]);
    u.z = pack_h2(s * acc[j8 * 8 + 4], s * acc[j8 * 8 + 5]);
    u.w = pack_h2(s * acc[j8 * 8 + 6], s * acc[j8 * 8 + 7]);
    yr[j8] = u;
  }
}

// ---------------------------------------------------------------------------
// Packed-half accumulate: w holds 2 fp16 features; v_dot2_f32_f16 with masks
// (1,0)/(0,1) accumulates each into its f32 lane accumulator.
// ---------------------------------------------------------------------------
typedef _Float16 half2r __attribute__((ext_vector_type(2)));

__device__ inline void dacc(unsigned w, float& a, float& b) {
  half2r v = __builtin_bit_cast(half2r, w);
  const half2r m10 = {(_Float16)1.0f, (_Float16)0.0f};
  const half2r m01 = {(_Float16)0.0f, (_Float16)1.0f};
  a = __builtin_amdgcn_fdot2(v, m10, a, false);
  b = __builtin_amdgcn_fdot2(v, m01, b, false);
}

__device__ inline void dacc4(uint4 u, float* acc) {
  dacc(u.x, acc[0], acc[1]); dacc(u.y, acc[2], acc[3]);
  dacc(u.z, acc[4], acc[5]); dacc(u.w, acc[6], acc[7]);
}

// ---------------------------------------------------------------------------
// Shuffle-free gather core with HOISTED INDEX LOADS: 8 lanes own one node;
// lane = feature-oct f. Per 16-edge chunk, ALL 16 idx loads issue up front
// (independent, contiguous -> broadcast-coalesced, in flight concurrently);
// the 4x4 row-load/accumulate batches then run back-to-back with addresses
// already resident — removes the per-step idx->row serialization (~200 cyc
// x4 per node). dacc order per accumulator is bitwise-identical to r9.
// ---------------------------------------------------------------------------
__device__ inline void agg_grp(const __half* __restrict__ Yf, int beg, int deg,
                               const int* __restrict__ srclist,
                               float* __restrict__ a, float* __restrict__ b) {
#pragma unroll
  for (int i = 0; i < 8; i++) { a[i] = 0.0f; b[i] = 0.0f; }
  for (int j0 = 0; j0 < deg; j0 += 16) {
    int m = deg - j0;
    if (m > 16) m = 16;
    const int* sp = srclist + beg + j0;
    int idx[16];
#pragma unroll
    for (int i = 0; i < 16; i++) idx[i] = (i < m) ? sp[i] : 0;
#pragma unroll
    for (int h = 0; h < 4; h++) {
      int i0 = h * 4;
      bool v0 = i0 < m, v1 = i0 + 1 < m, v2 = i0 + 2 < m, v3 = i0 + 3 < m;
      uint4 u0, u1, u2, u3;
      if (v0) u0 = *(const uint4*)(Yf + (size_t)idx[i0] * 64);
      if (v1) u1 = *(const uint4*)(Yf + (size_t)idx[i0 + 1] * 64);
      if (v2) u2 = *(const uint4*)(Yf + (size_t)idx[i0 + 2] * 64);
      if (v3) u3 = *(const uint4*)(Yf + (size_t)idx[i0 + 3] * 64);
      if (v0) dacc4(u0, a);
      if (v1) dacc4(u1, b);
      if (v2) dacc4(u2, a);
      if (v3) dacc4(u3, b);
    }
  }
}

// ---------------------------------------------------------------------------
// Fused: conv1 aggregation (group-per-node) + epilogue + conv2 input GEMM.
// W1 staged once per block (transposed, 16B-chunk XOR swizzle); hs padded
// [32][68]; same-wave LDS RAW, no barriers in the loop.
// ---------------------------------------------------------------------------
__global__ __launch_bounds__(256) void gather_mid(
    const __half* __restrict__ Y, const int* __restrict__ offs,
    const int* __restrict__ degv, const int* __restrict__ srclist,
    const float* __restrict__ b0, const float* __restrict__ csrc,
    const float* __restrict__ W1, __half* __restrict__ Y2) {
  __shared__ float WsT[64 * 64];  // [out][k], 16B chunk c = k4 ^ (out&7)
  __shared__ float hs[32][68];    // +4 pad: spread node rows across banks
  for (int i = threadIdx.x; i < 64 * 64; i += 256) {
    int k = i >> 6, o = i & 63;
    int c = (k >> 2) ^ (o & 7);
    WsT[o * 64 + (c << 2) + (k & 3)] = W1[i];
  }
  __syncthreads();
  int t = threadIdx.x;
  int lane = t & 63, wslot = t >> 6;
  int g = lane >> 3, f = lane & 7;
  int gs = wslot * 8 + g;  // node slot in block, 0..31
  float4 bv0 = ((const float4*)b0)[2 * f];
  float4 bv1 = ((const float4*)b0)[2 * f + 1];
  const __half* Yf = Y + 8 * f;
  for (int nbase = blockIdx.x * 32; nbase < N_NODES; nbase += MID_STRIDE) {
    int wid = nbase + gs;
    bool valid = wid < N_NODES;
    int beg = 0, deg = 0;
    if (valid) {
      beg = offs[wid];
      deg = degv[wid];
    }
    float a[8], b[8];
    agg_grp(Yf, beg, deg, srclist, a, b);
    float cd = deg > 0 ? rsqrtf((float)deg) : 0.0f;
    if (valid) {
      float4 h0, h1;
      h0.x = fmaxf((a[0] + b[0]) * cd + bv0.x, 0.0f);
      h0.y = fmaxf((a[1] + b[1]) * cd + bv0.y, 0.0f);
      h0.z = fmaxf((a[2] + b[2]) * cd + bv0.z, 0.0f);
      h0.w = fmaxf((a[3] + b[3]) * cd + bv0.w, 0.0f);
      h1.x = fmaxf((a[4] + b[4]) * cd + bv1.x, 0.0f);
      h1.y = fmaxf((a[5] + b[5]) * cd + bv1.y, 0.0f);
      h1.z = fmaxf((a[6] + b[6]) * cd + bv1.z, 0.0f);
      h1.w = fmaxf((a[7] + b[7]) * cd + bv1.w, 0.0f);
      *((float4*)&hs[gs][8 * f]) = h0;
      *((float4*)&hs[gs][8 * f + 4]) = h1;
    }
    // same-wave LDS RAW: in-order DS pipe, no barrier needed
    int node0 = nbase + wslot * 8;
#pragma unroll
    for (int nd = 0; nd < 8; nd++) {
      int node = node0 + nd;
      if (node >= N_NODES) break;  // wave-uniform
      float acc2 = 0.0f;
#pragma unroll
      for (int k4 = 0; k4 < 16; k4++) {
        float4 hv = *((const float4*)&hs[wslot * 8 + nd][4 * k4]);
        float4 w = *((const float4*)&WsT[lane * 64 + ((k4 ^ (lane & 7)) << 2)]);
        acc2 += hv.x * w.x + hv.y * w.y + hv.z * w.z + hv.w * w.w;
      }
      Y2[(size_t)node * 64 + lane] = __float2half(csrc[node] * acc2);
    }
  }
}

// ---------------------------------------------------------------------------
// Final aggregation + epilogue into z, group-per-node (no LDS beyond Wcs,
// no barriers in loop).
// MODE 0: z = relu(...)
// MODE 1: z -= relu(...), and emit uv[node] = {z.Wc_top(2), z.Wc_bot(2)}
// ---------------------------------------------------------------------------
template <int MODE>
__global__ __launch_bounds__(256) void gather_fin(
    const __half* __restrict__ Y2, const int* __restrict__ offs,
    const int* __restrict__ degv, const int* __restrict__ srclist,
    const float* __restrict__ b1, float* __restrict__ z,
    float* __restrict__ uv, const float* __restrict__ Wc) {
  __shared__ float Wcs[256];
  if (MODE == 1) {
    Wcs[threadIdx.x] = Wc[threadIdx.x];
    __syncthreads();
  }
  int t = threadIdx.x;
  int lane = t & 63, wslot = t >> 6;
  int g = lane >> 3, f = lane & 7;
  float4 bv0 = ((const float4*)b1)[2 * f];
  float4 bv1 = ((const float4*)b1)[2 * f + 1];
  const __half* Yf = Y2 + 8 * f;
  for (int nbase = blockIdx.x * 32; nbase < N_NODES; nbase += FIN_STRIDE) {
    int wid = nbase + wslot * 8 + g;
    bool valid = wid < N_NODES;
    int beg = 0, deg = 0;
    if (valid) {
      beg = offs[wid];
      deg = degv[wid];
    }
    float a[8], b[8];
    agg_grp(Yf, beg, deg, srclist, a, b);
    float cd = deg > 0 ? rsqrtf((float)deg) : 0.0f;
    float v[8];
    v[0] = fmaxf((a[0] + b[0]) * cd + bv0.x, 0.0f);
    v[1] = fmaxf((a[1] + b[1]) * cd + bv0.y, 0.0f);
    v[2] = fmaxf((a[2] + b[2]) * cd + bv0.z, 0.0f);
    v[3] = fmaxf((a[3] + b[3]) * cd + bv0.w, 0.0f);
    v[4] = fmaxf((a[4] + b[4]) * cd + bv1.x, 0.0f);
    v[5] = fmaxf((a[5] + b[5]) * cd + bv1.y, 0.0f);
    v[6] = fmaxf((a[6] + b[6]) * cd + bv1.z, 0.0f);
    v[7] = fmaxf((a[7] + b[7]) * cd + bv1.w, 0.0f);
    float* zrow = z + (size_t)wid * 64 + 8 * f;
    if (MODE == 0) {
      if (valid) {
        *((float4*)zrow) = make_float4(v[0], v[1], v[2], v[3]);
        *((float4*)(zrow + 4)) = make_float4(v[4], v[5], v[6], v[7]);
      }
    } else {
      float r[8];
      if (valid) {
        float4 zo0 = *((const float4*)zrow);
        float4 zo1 = *((const float4*)(zrow + 4));
        r[0] = zo0.x - v[0]; r[1] = zo0.y - v[1];
        r[2] = zo0.z - v[2]; r[3] = zo0.w - v[3];
        r[4] = zo1.x - v[4]; r[5] = zo1.y - v[5];
        r[6] = zo1.z - v[6]; r[7] = zo1.w - v[7];
        *((float4*)zrow) = make_float4(r[0], r[1], r[2], r[3]);
        *((float4*)(zrow + 4)) = make_float4(r[4], r[5], r[6], r[7]);
      } else {
#pragma unroll
        for (int i = 0; i < 8; i++) r[i] = 0.0f;
      }
      float pu0 = 0.0f, pu1 = 0.0f, pv0 = 0.0f, pv1 = 0.0f;
#pragma unroll
      for (int i = 0; i < 8; i++) {
        int j = 8 * f + i;
        pu0 += r[i] * Wcs[j * 2 + 0];
        pu1 += r[i] * Wcs[j * 2 + 1];
        pv0 += r[i] * Wcs[(64 + j) * 2 + 0];
        pv1 += r[i] * Wcs[(64 + j) * 2 + 1];
      }
#pragma unroll
      for (int o = 1; o < 8; o <<= 1) {  // reduce across the 8-lane group
        pu0 += __shfl_xor(pu0, o);
        pu1 += __shfl_xor(pu1, o);
        pv0 += __shfl_xor(pv0, o);
        pv1 += __shfl_xor(pv1, o);
      }
      if (valid && f == 0) {
        *((float4*)(uv + (size_t)wid * 4)) = make_float4(pu0, pu1, pv0, pv1);
      }
    }
  }
}

// ---------------------------------------------------------------------------
// probs[e] = sigmoid(u(s) + v(d) + bc)  — factorized classifier
// ---------------------------------------------------------------------------
__global__ __launch_bounds__(256) void classify_kernel(
    const float* __restrict__ uv, const int* __restrict__ ei,
    const float* __restrict__ bc, float* __restrict__ out) {
  int e = blockIdx.x * 256 + threadIdx.x;
  if (e >= E_QQ) return;
  int s = ei[e];
  int d = ei[E_QQ + e];
  float4 us = *((const float4*)(uv + (size_t)s * 4));
  float4 vd = *((const float4*)(uv + (size_t)d * 4));
  float l0 = us.x + vd.z + bc[0];
  float l1 = us.y + vd.w + bc[1];
  float2 o;
  o.x = 1.0f / (1.0f + __expf(-l0));
  o.y = 1.0f / (1.0f + __expf(-l1));
  *((float2*)(out + (size_t)e * 2)) = o;
}

extern "C" void kernel_launch(void* const* d_in, const int* in_sizes, int n_in,
                              void* d_out, int out_size, void* d_ws,
                              size_t ws_size, hipStream_t stream) {
  const float* x   = (const float*)d_in[0];
  const float* W0p = (const float*)d_in[1];
  const float* b0p = (const float*)d_in[2];
  const float* W0n = (const float*)d_in[3];
  const float* b0n = (const float*)d_in[4];
  const float* W1p = (const float*)d_in[5];
  const float* b1p = (const float*)d_in[6];
  const float* W1n = (const float*)d_in[7];
  const float* b1n = (const float*)d_in[8];
  const float* Wc  = (const float*)d_in[9];
  const float* bc  = (const float*)d_in[10];
  const int* sp = (const int*)d_in[11];
  const int* dp = (const int*)d_in[12];
  const int* sn = (const int*)d_in[13];
  const int* dn = (const int*)d_in[14];
  const int* ei = (const int*)d_in[15];

  // workspace layout (~53 MB)
  float* csrc_p = (float*)d_ws;                       // N
  float* csrc_n = csrc_p + N_NODES;                   // N
  int* offs_p = (int*)(csrc_n + N_NODES);             // N
  int* deg_p  = offs_p + N_NODES;                     // N
  int* offs_n = deg_p + N_NODES;                      // N
  int* deg_n  = offs_n + N_NODES;                     // N
  float* uv   = (float*)(deg_n + N_NODES);            // 4N
  int* gcur   = (int*)(uv + 4 * N_NODES);             // 2*NBUCK (+pad)
  unsigned* bin_d = (unsigned*)(gcur + 2 * NBUCK + 2);       // NBUCK*BCAP
  unsigned* bin_s = bin_d + (size_t)NBUCK * BCAP;            // NBUCK*BCAP
  int* srclist = (int*)(bin_s + (size_t)NBUCK * BCAP);       // NBUCK*BCAP
  __half* A = (__half*)(srclist + (size_t)NBUCK * BCAP);     // N*64 fp16
  __half* B = A + (size_t)N_NODES * 64;                      // N*64 fp16

  float* z     = (float*)d_out;                   // N*64 fp32
  float* probs = z + (size_t)N_NODES * 64;        // E_Q*2 fp32

  int* gcur_d = gcur;
  int* gcur_s = gcur + NBUCK;

  const int gemmGrid = (N_NODES + 255) / 256;

  // ---- POS relation ----
  hipMemsetAsync(gcur, 0, 2 * NBUCK * sizeof(int), stream);
  bin_edges<<<P1_BLOCKS, 256, 0, stream>>>(sp, dp, gcur_d, gcur_s, bin_d, bin_s);
  build_tables<<<2 * NBUCK, 256, 0, stream>>>(bin_d, gcur_d, bin_s, gcur_s,
                                              offs_p, deg_p, srclist, csrc_p);
  gemm_in_h<<<gemmGrid, 256, 0, stream>>>(x, W0p, csrc_p, A);
  gather_mid<<<MID_BLOCKS, 256, 0, stream>>>(A, offs_p, deg_p, srclist, b0p,
                                             csrc_p, W1p, B);
  gather_fin<0><<<FIN_BLOCKS, 256, 0, stream>>>(B, offs_p, deg_p, srclist, b1p,
                                                z, uv, Wc);

  // ---- NEG relation ---- (bins/srclist reused; pos consumers done)
  hipMemsetAsync(gcur, 0, 2 * NBUCK * sizeof(int), stream);
  bin_edges<<<P1_BLOCKS, 256, 0, stream>>>(sn, dn, gcur_d, gcur_s, bin_d, bin_s);
  build_tables<<<2 * NBUCK, 256, 0, stream>>>(bin_d, gcur_d, bin_s, gcur_s,
                                              offs_n, deg_n, srclist, csrc_n);
  gemm_in_h<<<gemmGrid, 256, 0, stream>>>(x, W0n, csrc_n, A);
  gather_mid<<<MID_BLOCKS, 256, 0, stream>>>(A, offs_n, deg_n, srclist, b0n,
                                             csrc_n, W1n, B);
  gather_fin<1><<<FIN_BLOCKS, 256, 0, stream>>>(B, offs_n, deg_n, srclist, b1n,
                                                z, uv, Wc);

  // ---- classifier (factorized) ----
  classify_kernel<<<(E_QQ + 255) / 256, 256, 0, stream>>>(uv, ei, bc, probs);
}

// Round 11
// 529.731 us; speedup vs baseline: 1.2271x; 1.2271x over previous
//
#include <hip/hip_runtime.h>
#include <hip/hip_fp16.h>
#include <math.h>

#define N_NODES 100000
#define DIM 64
#define E_REL 1600000
#define E_QQ 1000000

#define NBUCK 196      // ceil(100000 / 512) node buckets of 512
#define BCAP 9216      // capacity per bucket; expected 8192, +11 sigma slack
#define CHUNK_E 4096   // edges per phase-1 block -> 391 blocks (occupancy)
#define P1_BLOCKS ((E_REL + CHUNK_E - 1) / CHUNK_E)
#define MID_BLOCKS 1536            // 6 blocks/CU (25 KB LDS each)
#define MID_STRIDE (MID_BLOCKS * 32)
#define FIN_BLOCKS 2048            // 8 blocks/CU (1 KB LDS)
#define FIN_STRIDE (FIN_BLOCKS * 32)
#define GEMM_TILES ((N_NODES + 255) / 256)   // 391 row tiles

// ---------------------------------------------------------------------------
// Phase 1: bin edges by dst-bucket (packed (dlocal<<17)|src) and by src-bucket
// (raw src). Per-block LDS counts; ~2*NBUCK global atomics per block reserve
// space; placement via LDS cursors. int4-vectorized edge reads.
// ---------------------------------------------------------------------------
__global__ __launch_bounds__(256) void bin_edges(
    const int* __restrict__ src, const int* __restrict__ dst,
    int* __restrict__ gcur_d, int* __restrict__ gcur_s,
    unsigned* __restrict__ bin_d, unsigned* __restrict__ bin_s) {
  __shared__ int cd[NBUCK];
  __shared__ int cs[NBUCK];
  int t = threadIdx.x;
  for (int i = t; i < NBUCK; i += 256) { cd[i] = 0; cs[i] = 0; }
  __syncthreads();
  int e0 = blockIdx.x * CHUNK_E;
  int n = E_REL - e0;
  if (n > CHUNK_E) n = CHUNK_E;
  int n4 = n >> 2;  // chunk sizes (4096 / 2560 tail) are multiples of 4
  const int4* s4 = (const int4*)(src + e0);
  const int4* d4 = (const int4*)(dst + e0);
  for (int i = t; i < n4; i += 256) {
    int4 dv = d4[i];
    atomicAdd(&cd[dv.x >> 9], 1);
    atomicAdd(&cd[dv.y >> 9], 1);
    atomicAdd(&cd[dv.z >> 9], 1);
    atomicAdd(&cd[dv.w >> 9], 1);
    int4 sv = s4[i];
    atomicAdd(&cs[sv.x >> 9], 1);
    atomicAdd(&cs[sv.y >> 9], 1);
    atomicAdd(&cs[sv.z >> 9], 1);
    atomicAdd(&cs[sv.w >> 9], 1);
  }
  __syncthreads();
  for (int i = t; i < NBUCK; i += 256) {
    int c = cd[i];
    cd[i] = c > 0 ? atomicAdd(&gcur_d[i], c) : 0;
    c = cs[i];
    cs[i] = c > 0 ? atomicAdd(&gcur_s[i], c) : 0;
  }
  __syncthreads();
  for (int i = t; i < n4; i += 256) {
    int4 sv = s4[i];
    int4 dv = d4[i];
#pragma unroll
    for (int k = 0; k < 4; k++) {
      int s = (&sv.x)[k];
      int d = (&dv.x)[k];
      int bd = d >> 9;
      int bs = s >> 9;
      int pd = atomicAdd(&cd[bd], 1);
      int ps = atomicAdd(&cs[bs], 1);
      if ((unsigned)pd < BCAP)
        bin_d[(size_t)bd * BCAP + pd] = (unsigned)(((d & 511) << 17) | s);
      if ((unsigned)ps < BCAP)
        bin_s[(size_t)bs * BCAP + ps] = (unsigned)s;
    }
  }
}

// ---------------------------------------------------------------------------
// Phase 2 fused: blocks 0..NBUCK-1 build the dst-CSR with SLICE-ORDERED
// per-node src lists (4096-bin (dlocal<<3|src>>14) histogram -> scan ->
// compact). Blocks NBUCK..2*NBUCK-1 build csrc = rsqrt(outdeg).
// ---------------------------------------------------------------------------
__global__ __launch_bounds__(256) void build_tables(
    const unsigned* __restrict__ bin_d, const int* __restrict__ gcur_d,
    const unsigned* __restrict__ bin_s, const int* __restrict__ gcur_s,
    int* __restrict__ offs, int* __restrict__ degv, int* __restrict__ srclist,
    float* __restrict__ csrc) {
  __shared__ int cnt[4096];
  __shared__ int curv[4096];
  __shared__ int ls[256];
  int t = threadIdx.x;
  if (blockIdx.x >= NBUCK) {
    // ---- src histogram -> csrc ----
    int b = blockIdx.x - NBUCK;
    cnt[t] = 0;
    cnt[t + 256] = 0;
    __syncthreads();
    int n = gcur_s[b];
    if (n > BCAP) n = BCAP;
    const unsigned* be = bin_s + (size_t)b * BCAP;
    for (int i = t; i < n; i += 256) atomicAdd(&cnt[be[i] & 511], 1);
    __syncthreads();
    int node0 = b << 9;
    for (int i = t; i < 512; i += 256) {
      int node = node0 + i;
      if (node < N_NODES) {
        int d = cnt[i];
        csrc[node] = d > 0 ? rsqrtf((float)d) : 0.0f;
      }
    }
    return;
  }
  // ---- dst CSR, slice-ordered ----
  int b = blockIdx.x;
  for (int i = t; i < 4096; i += 256) cnt[i] = 0;
  __syncthreads();
  int n = gcur_d[b];
  if (n > BCAP) n = BCAP;
  const unsigned* be = bin_d + (size_t)b * BCAP;
  // bin = (dlocal<<3) | slice, slice = src>>14 in 0..6
  for (int i = t; i < n; i += 256) {
    unsigned p = be[i];
    int bin = (int)((p >> 17) << 3) | (int)((p & 0x1FFFFu) >> 14);
    atomicAdd(&cnt[bin], 1);
  }
  __syncthreads();
  // block scan over 4096 bins: 16 serial per thread + 256-wide scan
  int partial = 0;
#pragma unroll
  for (int i = 0; i < 16; i++) partial += cnt[t * 16 + i];
  ls[t] = partial;
  __syncthreads();
  for (int off = 1; off < 256; off <<= 1) {
    int v = (t >= off) ? ls[t - off] : 0;
    __syncthreads();
    ls[t] += v;
    __syncthreads();
  }
  int run = ls[t] - partial;
#pragma unroll
  for (int i = 0; i < 16; i++) {
    int bin = t * 16 + i;
    curv[bin] = run;
    run += cnt[bin];
  }
  __syncthreads();
  // write per-node outputs BEFORE placement mutates curv
  int node0 = b << 9;
  for (int i = t; i < 512; i += 256) {
    int node = node0 + i;
    if (node < N_NODES) {
      int deg = 0;
#pragma unroll
      for (int s = 0; s < 8; s++) deg += cnt[i * 8 + s];
      offs[node] = b * BCAP + curv[i * 8];
      degv[node] = deg;
    }
  }
  __syncthreads();
  for (int i = t; i < n; i += 256) {
    unsigned p = be[i];
    int bin = (int)((p >> 17) << 3) | (int)((p & 0x1FFFFu) >> 14);
    int pos = atomicAdd(&curv[bin], 1);
    srclist[(size_t)b * BCAP + pos] = (int)(p & 0x1FFFF);
  }
}

__device__ inline unsigned pack_h2(float a, float b) {
  __half2 h = __floats2half2_rn(a, b);
  return *reinterpret_cast<unsigned*>(&h);
}

// ---------------------------------------------------------------------------
// Y[row] = fp16( csrc[row] * (X[row] @ W) )
// Column-split: block bid = (tile, half); 256 rows x 32 cols per block.
// DS-issue fix: W staged as [64][32] half-tile, read as wave-uniform float4
// broadcasts -> 512 ds_read_b128 per row (was 4096 ds_read_b32).
// Grid 782 (2x) + acc in 8 float4 (VGPR ~65) -> ~12 waves/CU.
// ---------------------------------------------------------------------------
__global__ __launch_bounds__(256) void gemm_in_h(
    const float* __restrict__ X, const float* __restrict__ W,
    const float* __restrict__ csrc, __half* __restrict__ Y) {
  __shared__ float Ws[64][32];
  int half = blockIdx.x & 1;
  int tile = blockIdx.x >> 1;
  int c0 = half * 32;
  for (int i = threadIdx.x; i < 64 * 32; i += 256) {
    int k = i >> 5, j = i & 31;
    Ws[k][j] = W[k * 64 + c0 + j];
  }
  __syncthreads();
  int row = tile * 256 + threadIdx.x;
  if (row >= N_NODES) return;
  const float4* xr = (const float4*)(X + (size_t)row * 64);
  float4 acc[8];
#pragma unroll
  for (int j = 0; j < 8; j++) acc[j] = make_float4(0.f, 0.f, 0.f, 0.f);
#pragma unroll
  for (int k4 = 0; k4 < 16; k4++) {
    float4 xv = xr[k4];
    const float4* w0 = (const float4*)&Ws[k4 * 4 + 0][0];
    const float4* w1 = (const float4*)&Ws[k4 * 4 + 1][0];
    const float4* w2 = (const float4*)&Ws[k4 * 4 + 2][0];
    const float4* w3 = (const float4*)&Ws[k4 * 4 + 3][0];
#pragma unroll
    for (int j4 = 0; j4 < 8; j4++) {
      float4 a = w0[j4], b = w1[j4], c = w2[j4], d = w3[j4];
      acc[j4].x += xv.x * a.x + xv.y * b.x + xv.z * c.x + xv.w * d.x;
      acc[j4].y += xv.x * a.y + xv.y * b.y + xv.z * c.y + xv.w * d.y;
      acc[j4].z += xv.x * a.z + xv.y * b.z + xv.z * c.z + xv.w * d.z;
      acc[j4].w += xv.x * a.w + xv.y * b.w + xv.z * c.w + xv.w * d.w;
    }
  }
  float s = csrc[row];
  uint4* yr = (uint4*)(Y + (size_t)row * 64 + c0);
#pragma unroll
  for (int q = 0; q < 4; q++) {
    uint4 u;
    u.x = pack_h2(s * acc[2 * q].x, s * acc[2 * q].y);
    u.y = pack_h2(s * acc[2 * q].z, s * acc[2 * q].w);
    u.z = pack_h2(s * acc[2 * q + 1].x, s * acc[2 * q + 1].y);
    u.w = pack_h2(s * acc[2 * q + 1].z, s * acc[2 * q + 1].w);
    yr[q] = u;
  }
}

// ---------------------------------------------------------------------------
// Packed-half accumulate: w holds 2 fp16 features; v_dot2_f32_f16 with masks
// (1,0)/(0,1) accumulates each into its f32 lane accumulator.
// ---------------------------------------------------------------------------
typedef _Float16 half2r __attribute__((ext_vector_type(2)));

__device__ inline void dacc(unsigned w, float& a, float& b) {
  half2r v = __builtin_bit_cast(half2r, w);
  const half2r m10 = {(_Float16)1.0f, (_Float16)0.0f};
  const half2r m01 = {(_Float16)0.0f, (_Float16)1.0f};
  a = __builtin_amdgcn_fdot2(v, m10, a, false);
  b = __builtin_amdgcn_fdot2(v, m01, b, false);
}

__device__ inline void dacc4(uint4 u, float* acc) {
  dacc(u.x, acc[0], acc[1]); dacc(u.y, acc[2], acc[3]);
  dacc(u.z, acc[4], acc[5]); dacc(u.w, acc[6], acc[7]);
}

// ---------------------------------------------------------------------------
// Shuffle-free gather core (r9 form): 8 lanes own one node; lane = feature-
// oct f. Edge indices read directly from srclist (same addr across the
// 8-lane group -> broadcast-coalesced, L1-hot). 4 independent row loads in
// flight; NO cross-lane ops in the loop, no reduce. srclist is slice-ordered
// -> iteration j touches the j/deg quantile band of Y across all groups.
// ---------------------------------------------------------------------------
__device__ inline void agg_grp(const __half* __restrict__ Yf, int beg, int deg,
                               const int* __restrict__ srclist,
                               float* __restrict__ a, float* __restrict__ b) {
#pragma unroll
  for (int i = 0; i < 8; i++) { a[i] = 0.0f; b[i] = 0.0f; }
  for (int j = 0; j < deg; j += 4) {
    int i0 = beg + j, rem = deg - j;
    int x0 = srclist[i0];
    int x1 = rem > 1 ? srclist[i0 + 1] : x0;
    int x2 = rem > 2 ? srclist[i0 + 2] : x0;
    int x3 = rem > 3 ? srclist[i0 + 3] : x0;
    uint4 u0 = *(const uint4*)(Yf + (size_t)x0 * 64);
    uint4 u1 = *(const uint4*)(Yf + (size_t)x1 * 64);
    uint4 u2 = *(const uint4*)(Yf + (size_t)x2 * 64);
    uint4 u3 = *(const uint4*)(Yf + (size_t)x3 * 64);
    dacc4(u0, a);
    if (rem > 1) dacc4(u1, b);
    if (rem > 2) dacc4(u2, a);
    if (rem > 3) dacc4(u3, b);
  }
}

// ---------------------------------------------------------------------------
// Fused: conv1 aggregation (group-per-node) + epilogue + conv2 input GEMM.
// W1 staged once per block (transposed, 16B-chunk XOR swizzle); hs padded
// [32][68]; same-wave LDS RAW, no barriers in the loop.
// ---------------------------------------------------------------------------
__global__ __launch_bounds__(256) void gather_mid(
    const __half* __restrict__ Y, const int* __restrict__ offs,
    const int* __restrict__ degv, const int* __restrict__ srclist,
    const float* __restrict__ b0, const float* __restrict__ csrc,
    const float* __restrict__ W1, __half* __restrict__ Y2) {
  __shared__ float WsT[64 * 64];  // [out][k], 16B chunk c = k4 ^ (out&7)
  __shared__ float hs[32][68];    // +4 pad: spread node rows across banks
  for (int i = threadIdx.x; i < 64 * 64; i += 256) {
    int k = i >> 6, o = i & 63;
    int c = (k >> 2) ^ (o & 7);
    WsT[o * 64 + (c << 2) + (k & 3)] = W1[i];
  }
  __syncthreads();
  int t = threadIdx.x;
  int lane = t & 63, wslot = t >> 6;
  int g = lane >> 3, f = lane & 7;
  int gs = wslot * 8 + g;  // node slot in block, 0..31
  float4 bv0 = ((const float4*)b0)[2 * f];
  float4 bv1 = ((const float4*)b0)[2 * f + 1];
  const __half* Yf = Y + 8 * f;
  for (int nbase = blockIdx.x * 32; nbase < N_NODES; nbase += MID_STRIDE) {
    int wid = nbase + gs;
    bool valid = wid < N_NODES;
    int beg = 0, deg = 0;
    if (valid) {
      beg = offs[wid];
      deg = degv[wid];
    }
    float a[8], b[8];
    agg_grp(Yf, beg, deg, srclist, a, b);
    float cd = deg > 0 ? rsqrtf((float)deg) : 0.0f;
    if (valid) {
      float4 h0, h1;
      h0.x = fmaxf((a[0] + b[0]) * cd + bv0.x, 0.0f);
      h0.y = fmaxf((a[1] + b[1]) * cd + bv0.y, 0.0f);
      h0.z = fmaxf((a[2] + b[2]) * cd + bv0.z, 0.0f);
      h0.w = fmaxf((a[3] + b[3]) * cd + bv0.w, 0.0f);
      h1.x = fmaxf((a[4] + b[4]) * cd + bv1.x, 0.0f);
      h1.y = fmaxf((a[5] + b[5]) * cd + bv1.y, 0.0f);
      h1.z = fmaxf((a[6] + b[6]) * cd + bv1.z, 0.0f);
      h1.w = fmaxf((a[7] + b[7]) * cd + bv1.w, 0.0f);
      *((float4*)&hs[gs][8 * f]) = h0;
      *((float4*)&hs[gs][8 * f + 4]) = h1;
    }
    // same-wave LDS RAW: in-order DS pipe, no barrier needed
    int node0 = nbase + wslot * 8;
#pragma unroll
    for (int nd = 0; nd < 8; nd++) {
      int node = node0 + nd;
      if (node >= N_NODES) break;  // wave-uniform
      float acc2 = 0.0f;
#pragma unroll
      for (int k4 = 0; k4 < 16; k4++) {
        float4 hv = *((const float4*)&hs[wslot * 8 + nd][4 * k4]);
        float4 w = *((const float4*)&WsT[lane * 64 + ((k4 ^ (lane & 7)) << 2)]);
        acc2 += hv.x * w.x + hv.y * w.y + hv.z * w.z + hv.w * w.w;
      }
      Y2[(size_t)node * 64 + lane] = __float2half(csrc[node] * acc2);
    }
  }
}

// ---------------------------------------------------------------------------
// Final aggregation + epilogue into z, group-per-node (no LDS beyond Wcs,
// no barriers in loop).
// MODE 0: z = relu(...)
// MODE 1: z -= relu(...), and emit uv[node] = {z.Wc_top(2), z.Wc_bot(2)}
// ---------------------------------------------------------------------------
template <int MODE>
__global__ __launch_bounds__(256) void gather_fin(
    const __half* __restrict__ Y2, const int* __restrict__ offs,
    const int* __restrict__ degv, const int* __restrict__ srclist,
    const float* __restrict__ b1, float* __restrict__ z,
    float* __restrict__ uv, const float* __restrict__ Wc) {
  __shared__ float Wcs[256];
  if (MODE == 1) {
    Wcs[threadIdx.x] = Wc[threadIdx.x];
    __syncthreads();
  }
  int t = threadIdx.x;
  int lane = t & 63, wslot = t >> 6;
  int g = lane >> 3, f = lane & 7;
  float4 bv0 = ((const float4*)b1)[2 * f];
  float4 bv1 = ((const float4*)b1)[2 * f + 1];
  const __half* Yf = Y2 + 8 * f;
  for (int nbase = blockIdx.x * 32; nbase < N_NODES; nbase += FIN_STRIDE) {
    int wid = nbase + wslot * 8 + g;
    bool valid = wid < N_NODES;
    int beg = 0, deg = 0;
    if (valid) {
      beg = offs[wid];
      deg = degv[wid];
    }
    float a[8], b[8];
    agg_grp(Yf, beg, deg, srclist, a, b);
    float cd = deg > 0 ? rsqrtf((float)deg) : 0.0f;
    float v[8];
    v[0] = fmaxf((a[0] + b[0]) * cd + bv0.x, 0.0f);
    v[1] = fmaxf((a[1] + b[1]) * cd + bv0.y, 0.0f);
    v[2] = fmaxf((a[2] + b[2]) * cd + bv0.z, 0.0f);
    v[3] = fmaxf((a[3] + b[3]) * cd + bv0.w, 0.0f);
    v[4] = fmaxf((a[4] + b[4]) * cd + bv1.x, 0.0f);
    v[5] = fmaxf((a[5] + b[5]) * cd + bv1.y, 0.0f);
    v[6] = fmaxf((a[6] + b[6]) * cd + bv1.z, 0.0f);
    v[7] = fmaxf((a[7] + b[7]) * cd + bv1.w, 0.0f);
    float* zrow = z + (size_t)wid * 64 + 8 * f;
    if (MODE == 0) {
      if (valid) {
        *((float4*)zrow) = make_float4(v[0], v[1], v[2], v[3]);
        *((float4*)(zrow + 4)) = make_float4(v[4], v[5], v[6], v[7]);
      }
    } else {
      float r[8];
      if (valid) {
        float4 zo0 = *((const float4*)zrow);
        float4 zo1 = *((const float4*)(zrow + 4));
        r[0] = zo0.x - v[0]; r[1] = zo0.y - v[1];
        r[2] = zo0.z - v[2]; r[3] = zo0.w - v[3];
        r[4] = zo1.x - v[4]; r[5] = zo1.y - v[5];
        r[6] = zo1.z - v[6]; r[7] = zo1.w - v[7];
        *((float4*)zrow) = make_float4(r[0], r[1], r[2], r[3]);
        *((float4*)(zrow + 4)) = make_float4(r[4], r[5], r[6], r[7]);
      } else {
#pragma unroll
        for (int i = 0; i < 8; i++) r[i] = 0.0f;
      }
      float pu0 = 0.0f, pu1 = 0.0f, pv0 = 0.0f, pv1 = 0.0f;
#pragma unroll
      for (int i = 0; i < 8; i++) {
        int j = 8 * f + i;
        pu0 += r[i] * Wcs[j * 2 + 0];
        pu1 += r[i] * Wcs[j * 2 + 1];
        pv0 += r[i] * Wcs[(64 + j) * 2 + 0];
        pv1 += r[i] * Wcs[(64 + j) * 2 + 1];
      }
#pragma unroll
      for (int o = 1; o < 8; o <<= 1) {  // reduce across the 8-lane group
        pu0 += __shfl_xor(pu0, o);
        pu1 += __shfl_xor(pu1, o);
        pv0 += __shfl_xor(pv0, o);
        pv1 += __shfl_xor(pv1, o);
      }
      if (valid && f == 0) {
        *((float4*)(uv + (size_t)wid * 4)) = make_float4(pu0, pu1, pv0, pv1);
      }
    }
  }
}

// ---------------------------------------------------------------------------
// probs[e] = sigmoid(u(s) + v(d) + bc)  — factorized classifier
// ---------------------------------------------------------------------------
__global__ __launch_bounds__(256) void classify_kernel(
    const float* __restrict__ uv, const int* __restrict__ ei,
    const float* __restrict__ bc, float* __restrict__ out) {
  int e = blockIdx.x * 256 + threadIdx.x;
  if (e >= E_QQ) return;
  int s = ei[e];
  int d = ei[E_QQ + e];
  float4 us = *((const float4*)(uv + (size_t)s * 4));
  float4 vd = *((const float4*)(uv + (size_t)d * 4));
  float l0 = us.x + vd.z + bc[0];
  float l1 = us.y + vd.w + bc[1];
  float2 o;
  o.x = 1.0f / (1.0f + __expf(-l0));
  o.y = 1.0f / (1.0f + __expf(-l1));
  *((float2*)(out + (size_t)e * 2)) = o;
}

extern "C" void kernel_launch(void* const* d_in, const int* in_sizes, int n_in,
                              void* d_out, int out_size, void* d_ws,
                              size_t ws_size, hipStream_t stream) {
  const float* x   = (const float*)d_in[0];
  const float* W0p = (const float*)d_in[1];
  const float* b0p = (const float*)d_in[2];
  const float* W0n = (const float*)d_in[3];
  const float* b0n = (const float*)d_in[4];
  const float* W1p = (const float*)d_in[5];
  const float* b1p = (const float*)d_in[6];
  const float* W1n = (const float*)d_in[7];
  const float* b1n = (const float*)d_in[8];
  const float* Wc  = (const float*)d_in[9];
  const float* bc  = (const float*)d_in[10];
  const int* sp = (const int*)d_in[11];
  const int* dp = (const int*)d_in[12];
  const int* sn = (const int*)d_in[13];
  const int* dn = (const int*)d_in[14];
  const int* ei = (const int*)d_in[15];

  // workspace layout (~53 MB)
  float* csrc_p = (float*)d_ws;                       // N
  float* csrc_n = csrc_p + N_NODES;                   // N
  int* offs_p = (int*)(csrc_n + N_NODES);             // N
  int* deg_p  = offs_p + N_NODES;                     // N
  int* offs_n = deg_p + N_NODES;                      // N
  int* deg_n  = offs_n + N_NODES;                     // N
  float* uv   = (float*)(deg_n + N_NODES);            // 4N
  int* gcur   = (int*)(uv + 4 * N_NODES);             // 2*NBUCK (+pad)
  unsigned* bin_d = (unsigned*)(gcur + 2 * NBUCK + 2);       // NBUCK*BCAP
  unsigned* bin_s = bin_d + (size_t)NBUCK * BCAP;            // NBUCK*BCAP
  int* srclist = (int*)(bin_s + (size_t)NBUCK * BCAP);       // NBUCK*BCAP
  __half* A = (__half*)(srclist + (size_t)NBUCK * BCAP);     // N*64 fp16
  __half* B = A + (size_t)N_NODES * 64;                      // N*64 fp16

  float* z     = (float*)d_out;                   // N*64 fp32
  float* probs = z + (size_t)N_NODES * 64;        // E_Q*2 fp32

  int* gcur_d = gcur;
  int* gcur_s = gcur + NBUCK;

  // ---- POS relation ----
  hipMemsetAsync(gcur, 0, 2 * NBUCK * sizeof(int), stream);
  bin_edges<<<P1_BLOCKS, 256, 0, stream>>>(sp, dp, gcur_d, gcur_s, bin_d, bin_s);
  build_tables<<<2 * NBUCK, 256, 0, stream>>>(bin_d, gcur_d, bin_s, gcur_s,
                                              offs_p, deg_p, srclist, csrc_p);
  gemm_in_h<<<GEMM_TILES * 2, 256, 0, stream>>>(x, W0p, csrc_p, A);
  gather_mid<<<MID_BLOCKS, 256, 0, stream>>>(A, offs_p, deg_p, srclist, b0p,
                                             csrc_p, W1p, B);
  gather_fin<0><<<FIN_BLOCKS, 256, 0, stream>>>(B, offs_p, deg_p, srclist, b1p,
                                                z, uv, Wc);

  // ---- NEG relation ---- (bins/srclist reused; pos consumers done)
  hipMemsetAsync(gcur, 0, 2 * NBUCK * sizeof(int), stream);
  bin_edges<<<P1_BLOCKS, 256, 0, stream>>>(sn, dn, gcur_d, gcur_s, bin_d, bin_s);
  build_tables<<<2 * NBUCK, 256, 0, stream>>>(bin_d, gcur_d, bin_s, gcur_s,
                                              offs_n, deg_n, srclist, csrc_n);
  gemm_in_h<<<GEMM_TILES * 2, 256, 0, stream>>>(x, W0n, csrc_n, A);
  gather_mid<<<MID_BLOCKS, 256, 0, stream>>>(A, offs_n, deg_n, srclist, b0n,
                                             csrc_n, W1n, B);
  gather_fin<1><<<FIN_BLOCKS, 256, 0, stream>>>(B, offs_n, deg_n, srclist, b1n,
                                                z, uv, Wc);

  // ---- classifier (factorized) ----
  classify_kernel<<<(E_QQ + 255) / 256, 256, 0, stream>>>(uv, ei, bc, probs);
}